// Round 11
// baseline (103.137 us; speedup 1.0000x reference)
//
#include <hip/hip_runtime.h>

// ---------------------------------------------------------------------------
// HierarchicalAffinityLoss on MI355X, fp16-MFMA, round 22 (= R21 resubmit;
// R21 bench was an infra failure — container died twice, no output; desk
// re-audit found no kernel-side hazard: uniform barriers, colS read/write
// separated by barriers, diagonal col-merge matches R17's passing
// semantics, staging is an identity copy as in R20).
// loss = mean_r relu(maxDot_diff(r) - minDot_same(r) + 0.3), dots of
// row-normalized embeddings. Self-exclusion via bias rank.
// R20 post-mortem: 103us total (best). gram ~36us by subtraction (fixed
// ~67us = 44us harness 256MiB ws-poison fill + ~20us prep/reduce/launch).
// Remaining gram gap vs ~12-19us floors: the per-task barrier drains
// vmcnt(0), WHICH COUNTS GLOBAL ATOMICS — each task's 512 contended
// col-side lane-atomics (hot 64-address range shared by ~33 blocks) must
// complete before any wave crosses the barrier. R17 (no barriers) never
// waited on them; R20's barrier reintroduced the wait.
// R21/R22: defer col-side atomics off the drain path:
//  * per task, waves write packed (mn,mx) fp16 col partials to LDS
//    colS[f&1][w][64] (idle waves write SENT);
//  * after the NEXT barrier, lanes<16 of each wave pkmin-fold the 4
//    partials for 16 cols and issue the atomics: 128 lane-atomics per
//    block-task (4x fewer), a full task (~3-10k cyc) before any barrier
//    waits on them -> drain ~free. Diagonal tiles write real values
//    (min/max idempotent). Tail merge after a final barrier.
// Everything else = R20: 2-phase LDS dbuf staging from fragment-linear
// EhB (stage FIRST, then compute), A-panel in regs, bias rank K=288
// (dot' = dot - 8*[same]), row-side reg accumulation flushed at every
// rb-crossing (R15 fix), triangle tasks, grid 512, XCD swizzle.
// ---------------------------------------------------------------------------

typedef __attribute__((ext_vector_type(8))) _Float16 half8;  // MFMA A/B frag
typedef __attribute__((ext_vector_type(2))) _Float16 half2v;
typedef __attribute__((ext_vector_type(4))) float floatx4;   // MFMA C/D
typedef __attribute__((ext_vector_type(4))) unsigned short ushort4v;

constexpr int DIN = 256;  // input embedding dim
constexpr int NKS = 9;    // K blocks of 32: 8 data + 1 bias
// fragment-linear tile: [ks 0..8][nj 0..3][lane 0..63][8 halves]
constexpr int TILE_USH = NKS * 4 * 64 * 8;   // 18432 ushorts = 36KB per tile
#define MARGIN 0.3f
// packed family table {0,1,2,1,3,3}, 3 bits each
#define FAM_PACKED 111240
#define SENT 0xC4004400u  // packmm(4.0f, -4.0f): (mn, mx) neutral pair

static __device__ __forceinline__ unsigned fkey(float x) {
  return __builtin_bit_cast(unsigned, x + 10.0f);  // touched values > 0
}
static __device__ __forceinline__ unsigned packmm(float mn, float mx) {
  unsigned lo = __builtin_bit_cast(unsigned short, (_Float16)mn);
  unsigned hi = __builtin_bit_cast(unsigned short, (_Float16)mx);
  return lo | (hi << 16);
}
static __device__ __forceinline__ float mmlo(unsigned p) {
  return (float)__builtin_bit_cast(_Float16, (unsigned short)(p & 0xFFFF));
}
static __device__ __forceinline__ float mmhi(unsigned p) {
  return (float)__builtin_bit_cast(_Float16, (unsigned short)(p >> 16));
}
// packed elementwise fp16 min -> v_pk_min_f16
static __device__ __forceinline__ unsigned pkmin(unsigned a, unsigned b) {
  half2v x = __builtin_bit_cast(half2v, a);
  half2v y = __builtin_bit_cast(half2v, b);
  return __builtin_bit_cast(unsigned, __builtin_elementwise_min(x, y));
}

// async 16B global -> LDS (wave-uniform LDS base; HW adds lane*16)
static __device__ __forceinline__ void ld_g2l16(const unsigned short* g,
                                                unsigned short* lds) {
  __builtin_amdgcn_global_load_lds(
      (const __attribute__((address_space(1))) unsigned int*)(const void*)g,
      (__attribute__((address_space(3))) unsigned int*)(void*)lds, 16, 0, 0);
}

// K1: grid-stride waves; row r -> tile ct=r>>6, nj=(r>>4)&3, mrow=r&15.
// Lane holds elems e=lane*4..+3: ks=lane>>3, q=(lane>>1)&3, o=(lane&1)*4.
// EhB[((ct*9+ks)*4+nj)*512 + (q*16+mrow)*8 + o] = fp16(E/||E||) (e<256);
// ks=8 block: 4*onehot(fam) at e=256..259, zeros elsewhere.
__global__ __launch_bounds__(256) void prep_kernel(
    const float* __restrict__ E, const int* __restrict__ labels,
    unsigned short* __restrict__ EhB, unsigned* __restrict__ mnK,
    unsigned* __restrict__ mxK, float* __restrict__ sumAcc,
    int* __restrict__ cntAcc, int* __restrict__ doneCnt, int B) {
  if (blockIdx.x == 0 && threadIdx.x == 0) {
    sumAcc[0] = 0.0f; cntAcc[0] = 0; doneCnt[0] = 0;
  }
  int gid = blockIdx.x * 256 + threadIdx.x;
  if (gid < B) { mnK[gid] = 0xFFFFFFFFu; mxK[gid] = 0u; }
  int wave = blockIdx.x * 4 + (threadIdx.x >> 6);
  int lane = threadIdx.x & 63;
  int nw   = gridDim.x * 4;
  const int ksl = lane >> 3, ql = (lane >> 1) & 3, ol = (lane & 1) * 4;
  for (int row = wave; row < B; row += nw) {
    float4 v = *(const float4*)&E[(long)row * DIN + lane * 4];
    float s = v.x * v.x + v.y * v.y + v.z * v.z + v.w * v.w;
#pragma unroll
    for (int o = 1; o < 64; o <<= 1) s += __shfl_xor(s, o);
    float rn = 1.0f / sqrtf(s);
    ushort4v o4;
    o4.x = __builtin_bit_cast(unsigned short, (_Float16)(v.x * rn));
    o4.y = __builtin_bit_cast(unsigned short, (_Float16)(v.y * rn));
    o4.z = __builtin_bit_cast(unsigned short, (_Float16)(v.z * rn));
    o4.w = __builtin_bit_cast(unsigned short, (_Float16)(v.w * rn));
    const int ct = row >> 6, nj = (row >> 4) & 3, mrow = row & 15;
    const long tbase = (long)ct * TILE_USH;
    *(ushort4v*)&EhB[tbase + ((long)(ksl * 4 + nj) * 64 + ql * 16 + mrow) * 8
                     + ol] = o4;
    if (lane < 8) {   // bias block ks=8: elems 256..287
      ushort4v z = {0, 0, 0, 0};
      if (lane == 0) {
        int lab = labels[row];
        int labc = lab < 0 ? 0 : (lab > 5 ? 5 : lab);
        int fm = (FAM_PACKED >> (3 * labc)) & 7;
        z.x = fm == 0 ? 0x4400 : 0;   // 4.0h
        z.y = fm == 1 ? 0x4400 : 0;
        z.z = fm == 2 ? 0x4400 : 0;
        z.w = fm == 3 ? 0x4400 : 0;
      }
      *(ushort4v*)&EhB[tbase + ((long)(8 * 4 + nj) * 64 + ql * 16 + mrow) * 8
                       + ol] = z;
    }
  }
}

// K2: block = 4 waves. Wave w owns rows rb*128+w*32 (A tile 2rb+(w>>1),
// frag cols (w&1)*2+mi) in regs. Per task: B tile (36KB) staged once into
// LDS dbuf via global_load_lds, 2-phase: barrier -> stage next (async) ->
// merge prev col partials (deferred atomics) -> compute current from LDS.
__global__ __launch_bounds__(256, 2) void gram_kernel(
    const unsigned short* __restrict__ EhB, unsigned* __restrict__ mnK,
    unsigned* __restrict__ mxK, int nt, int nTasks) {
  __shared__ unsigned short Bs[2][TILE_USH];   // 2 x 36KB
  __shared__ unsigned colS[2][4][64];          // 2KB packed (mn,mx) fp16

  const int w = threadIdx.x >> 6, l = threadIdx.x & 63;
  const int m = l & 15, q = l >> 4;

  // bijective XCD swizzle (gridDim % 8 == 0)
  const int nwg = gridDim.x;
  const int bid = (int)blockIdx.x;
  const int swz = (bid & 7) * (nwg >> 3) + (bid >> 3);

  const int t0 = (int)(((long)swz * nTasks) / nwg);
  const int t1 = (int)(((long)(swz + 1) * nTasks) / nwg);

  // decode t0 -> (rb, ct): C(rb) = rb*(nt-rb+1); C(rb+1) = (rb+1)*(nt-rb)
  int rb = 0;
  while ((rb + 1) * (nt - rb) <= t0) ++rb;
  int ct = 2 * rb + (t0 - rb * (nt - rb + 1));

  const unsigned short* baseL = EhB + l * 8;   // lane's fragment column (A)

  // stage B tile ctv into Bs[buf]: thread chunk j*256 + w*64 + l
  auto stage = [&](int buf, int ctv) {
    const unsigned short* src =
        EhB + (long)ctv * TILE_USH + (long)(w * 64 + l) * 8;
    unsigned short* dst = &Bs[buf][(w * 64) * 8];
#pragma unroll
    for (int j = 0; j < 9; ++j)
      ld_g2l16(src + j * 2048, dst + j * 2048);
  };

  half8 apan[NKS][2];   // 8 data K-blocks + bias (pre-scaled -0.5)
  auto loadA = [&](int rbv) {
    const long at = (long)(2 * rbv + (w >> 1)) * TILE_USH;
#pragma unroll
    for (int ks = 0; ks < NKS; ++ks)
#pragma unroll
      for (int mi = 0; mi < 2; ++mi)
        apan[ks][mi] = *(const half8*)
            &baseL[at + (long)(ks * 4 + (w & 1) * 2 + mi) * 512];
    apan[8][0] = apan[8][0] * (_Float16)-0.5f;   // 4*onehot -> -2*onehot
    apan[8][1] = apan[8][1] * (_Float16)-0.5f;
  };
  loadA(rb);

  float rAmn[8], rAmx[8];
  bool any = false;
#pragma unroll
  for (int i = 0; i < 8; ++i) { rAmn[i] = 100.0f; rAmx[i] = -100.0f; }

  auto flushRows = [&](int rbv) {
    if (!any) return;
#pragma unroll
    for (int o = 1; o < 16; o <<= 1)
#pragma unroll
      for (int i = 0; i < 8; ++i) {
        rAmn[i] = fminf(rAmn[i], __shfl_xor(rAmn[i], o));
        rAmx[i] = fmaxf(rAmx[i], __shfl_xor(rAmx[i], o));
      }
    if (m == 0) {
      const int r0 = rbv * 128 + w * 32 + q * 4;
#pragma unroll
      for (int mi = 0; mi < 2; ++mi)
#pragma unroll
        for (int r = 0; r < 4; ++r) {
          int row = r0 + mi * 16 + r;
          atomicMin(&mnK[row], fkey(rAmn[mi * 4 + r]));
          atomicMax(&mxK[row], fkey(rAmx[mi * 4 + r]));
        }
    }
  };

  // deferred col merge: fold 4 waves' partials for 16 cols, then atomics
  auto mergeCols = [&](int pct, int sb2) {
    if (l >= 16) return;
    unsigned a = SENT ^ 0x80000000u;   // (4.0, 4.0) pk-min neutral
#pragma unroll
    for (int ww = 0; ww < 4; ++ww)
      a = pkmin(a, colS[sb2][ww][w * 16 + l] ^ 0x80000000u);
    a ^= 0x80000000u;
    float mn = mmlo(a), mx = mmhi(a);
    int col = pct * 64 + w * 16 + l;
    if (mn < 3.9f) atomicMin(&mnK[col], fkey(mn));   // skip all-sentinel
    if (mx > -3.9f) atomicMax(&mxK[col], fkey(mx));
  };

  stage(0, ct);   // prologue: first tile into buffer 0
  int p = 0, pct = -1;

#pragma unroll 1
  for (int f = t0; f < t1; ++f) {
    __syncthreads();   // buf[p] staged; prev colS writes visible

    // next task coords (needed for prefetch target)
    int nct = ct + 1, nrb = rb;
    if (nct == nt) { ++nrb; nct = 2 * nrb; }
    if (f + 1 < t1) stage(p ^ 1, nct);   // async prefetch FIRST

    // deferred col-side atomics for task f-1 (complete during compute;
    // next barrier's vmcnt drain sees them long done)
    if (pct >= 0) mergeCols(pct, (f - 1) & 1);

    const int rt64 = 2 * rb + (w >> 1);
    const int sb = f & 1;
    if (rt64 <= ct) {
      any = true;
      floatx4 acc[2][4];
#pragma unroll
      for (int mi = 0; mi < 2; ++mi)
#pragma unroll
        for (int nj = 0; nj < 4; ++nj) acc[mi][nj] = (floatx4)0.0f;
#pragma unroll
      for (int ks = 0; ks < NKS; ++ks) {
        half8 b[4];
#pragma unroll
        for (int nj = 0; nj < 4; ++nj)
          b[nj] = *(const half8*)&Bs[p][((ks * 4 + nj) * 64 + l) * 8];
#pragma unroll
        for (int mi = 0; mi < 2; ++mi)
#pragma unroll
          for (int nj = 0; nj < 4; ++nj)
            acc[mi][nj] = __builtin_amdgcn_mfma_f32_16x16x32_f16(
                apan[ks][mi], b[nj], acc[mi][nj], 0, 0, 0);
      }
      // ---- epilogue: biased extremes; C/D col = nj*16+m, row = mi*16+q*4+r
      float cMn[4], cMx[4];
#pragma unroll
      for (int nj = 0; nj < 4; ++nj) {
        float a0 = fminf(fminf(acc[0][nj][0], acc[0][nj][1]),
                         fminf(acc[0][nj][2], acc[0][nj][3]));
        float a1 = fminf(fminf(acc[1][nj][0], acc[1][nj][1]),
                         fminf(acc[1][nj][2], acc[1][nj][3]));
        float b0 = fmaxf(fmaxf(acc[0][nj][0], acc[0][nj][1]),
                         fmaxf(acc[0][nj][2], acc[0][nj][3]));
        float b1 = fmaxf(fmaxf(acc[1][nj][0], acc[1][nj][1]),
                         fmaxf(acc[1][nj][2], acc[1][nj][3]));
        cMn[nj] = fminf(a0, a1);
        cMx[nj] = fmaxf(b0, b1);
#pragma unroll
        for (int mi = 0; mi < 2; ++mi)
#pragma unroll
          for (int r = 0; r < 4; ++r) {
            rAmn[mi * 4 + r] = fminf(rAmn[mi * 4 + r], acc[mi][nj][r]);
            rAmx[mi * 4 + r] = fmaxf(rAmx[mi * 4 + r], acc[mi][nj][r]);
          }
      }
#pragma unroll
      for (int nj = 0; nj < 4; ++nj) {
        cMn[nj] = fminf(cMn[nj], __shfl_xor(cMn[nj], 16));
        cMn[nj] = fminf(cMn[nj], __shfl_xor(cMn[nj], 32));
        cMx[nj] = fmaxf(cMx[nj], __shfl_xor(cMx[nj], 16));
        cMx[nj] = fmaxf(cMx[nj], __shfl_xor(cMx[nj], 32));
      }
      if (q == 0) {   // packed (mn,mx); diagonal writes real (idempotent)
#pragma unroll
        for (int nj = 0; nj < 4; ++nj)
          colS[sb][w][nj * 16 + m] = packmm(cMn[nj], cMx[nj]);
      }
    } else {
      if (q == 0)
#pragma unroll
        for (int nj = 0; nj < 4; ++nj) colS[sb][w][nj * 16 + m] = SENT;
    }

    // advance; flush on EVERY rb-crossing (R15 fix)
    if (nrb != rb) {
      flushRows(rb);
#pragma unroll
      for (int i = 0; i < 8; ++i) { rAmn[i] = 100.0f; rAmx[i] = -100.0f; }
      any = false;
      if (f + 1 < t1) loadA(nrb);
    }
    pct = ct; rb = nrb; ct = nct; p ^= 1;
  }
  __syncthreads();                      // last task's colS visible
  mergeCols(pct, (t1 - 1) & 1);         // tail merge
  flushRows(rb);   // no-op (any==false) if last task closed an rb
}

// K3: one thread per row. biasedMin = f(mnK)-10 (= minSame-8 iff < -4);
// biasedMax = f(mxK)-10 (= maxDiff iff > -4).
__global__ __launch_bounds__(256) void reduce_kernel(
    const unsigned* __restrict__ mnK, const unsigned* __restrict__ mxK,
    float* __restrict__ sumAcc, int* __restrict__ cntAcc,
    int* __restrict__ doneCnt, float* __restrict__ out, int B) {
  int gid = blockIdx.x * 256 + threadIdx.x;
  float loss = 0.0f;
  int cc = 0;
  if (gid < B) {
    float bmn = __builtin_bit_cast(float, mnK[gid]) - 10.0f;
    float bmx = __builtin_bit_cast(float, mxK[gid]) - 10.0f;
    if (bmn < -4.0f && bmx > -4.0f) {   // has same && has diff
      loss = fmaxf(bmx - (bmn + 8.0f) + MARGIN, 0.0f);
      cc = 1;
    }
  }
#pragma unroll
  for (int o = 1; o < 64; o <<= 1) {
    loss += __shfl_xor(loss, o);
    cc   += __shfl_xor(cc, o);
  }
  __shared__ float ls[4];
  __shared__ int   cs[4];
  if ((threadIdx.x & 63) == 0) {
    ls[threadIdx.x >> 6] = loss;
    cs[threadIdx.x >> 6] = cc;
  }
  __syncthreads();
  if (threadIdx.x == 0) {
    atomicAdd(sumAcc, ls[0] + ls[1] + ls[2] + ls[3]);
    atomicAdd(cntAcc, cs[0] + cs[1] + cs[2] + cs[3]);
    __threadfence();
    int old = atomicAdd(doneCnt, 1);
    if (old == (int)gridDim.x - 1) {
      float S = atomicAdd(sumAcc, 0.0f);   // coherent read
      int   C = atomicAdd(cntAcc, 0);
      out[0] = S / (float)(C > 0 ? C : 1);
    }
  }
}

extern "C" void kernel_launch(void* const* d_in, const int* in_sizes, int n_in,
                              void* d_out, int out_size, void* d_ws, size_t ws_size,
                              hipStream_t stream) {
  const float* E      = (const float*)d_in[0];
  const int*   labels = (const int*)d_in[1];
  float*       out    = (float*)d_out;
  const int B  = in_sizes[1];        // 8192
  const int nt = B / 64;             // 128 col tiles
  const int RB = B / 128;            // 64 row panels of 128 rows
  const int nTasks = RB * (nt - RB + 1);   // 64*65 = 4160

  // ws: EhB[nt*36KB] (4.72MB) | mnK[B] | mxK[B] | accums  (~4.79MB)
  unsigned short* EhB = (unsigned short*)d_ws;
  unsigned* mnK       = (unsigned*)(EhB + (size_t)nt * TILE_USH);
  unsigned* mxK       = mnK + B;
  float* sumAcc       = (float*)(mxK + B);
  int* cntAcc         = (int*)(sumAcc + 1);
  int* doneCnt        = cntAcc + 1;

  prep_kernel<<<dim3(256), 256, 0, stream>>>(E, labels, EhB, mnK, mxK,
                                             sumAcc, cntAcc, doneCnt, B);
  // grid 512 = exactly 2 blocks/CU (LDS 74KB/block caps residency at 2)
  gram_kernel<<<dim3(512), 256, 0, stream>>>(EhB, mnK, mxK, nt, nTasks);
  reduce_kernel<<<dim3((B + 255) / 256), 256, 0, stream>>>(
      mnK, mxK, sumAcc, cntAcc, doneCnt, out, B);
}